// Round 3
// baseline (218.633 us; speedup 1.0000x reference)
//
#include <hip/hip_runtime.h>
#include <math.h>

#define NPTS 8192
#define NB   128
#define EPS  1.1920929e-07f

__device__ __forceinline__ float rdlane(float v, int l) {
    return __int_as_float(__builtin_amdgcn_readlane(__float_as_int(v), l));
}

// ---------------------------------------------------------------------------
// K1: per-ball prep:  a = rmsnorm(x)*n1w + (pos - ball_mean(pos))
//     A2[b][h][m][e] (each (b,h) slice contiguous 2KB)
//     bm2[h][b][e]   routing keys (per-lane float4-loadable)
//     blocks >= NB pack MLP weights: w12 (w1/w2 interleaved), w3P (k-paired).
// ---------------------------------------------------------------------------
__global__ __launch_bounds__(256) void k_prep(
    const float* __restrict__ x, const float* __restrict__ pos,
    const float* __restrict__ n1w,
    const float* __restrict__ w1, const float* __restrict__ w2,
    const float* __restrict__ w3,
    float* __restrict__ A2, float* __restrict__ bm2,
    float* __restrict__ w12, float* __restrict__ w3P)
{
    int t = threadIdx.x;
    int blk = blockIdx.x;
    if (blk >= NB) {
        int base = (blk - NB) * 1024 + t * 4;
        #pragma unroll
        for (int c = 0; c < 4; ++c) {
            int idx = base + c;
            if (idx < 32768) {
                // w12[e*512 + u*128 + l*2 + s] = (s?w2:w1)[(u*64+l)*64 + e]
                int s = idx & 1, l = (idx >> 1) & 63, u = (idx >> 7) & 3, e = idx >> 9;
                w12[idx] = (s ? w2 : w1)[(u * 64 + l) * 64 + e];
            } else {
                // w3P[kp*128 + l*2 + s] = w3[l*256 + kp*2 + s]
                int o = idx - 32768;
                int s = o & 1, l = (o >> 1) & 63, kp = o >> 7;
                w3P[o] = w3[l * 256 + kp * 2 + s];
            }
        }
        return;
    }
    __shared__ float xs[64 * 68];
    __shared__ float ps[64 * 68];
    __shared__ float red[256], red2[256];
    __shared__ float pm[64], rs[64], nw[64];

    const float* xb = x + blk * 4096;
    const float* pb = pos + blk * 4096;
    if (t < 64) nw[t] = n1w[t];
    #pragma unroll
    for (int it = 0; it < 4; ++it) {
        int o4 = t + it * 256;
        int row = o4 >> 4, col = (o4 & 15) * 4;
        float4 xv = ((const float4*)xb)[o4];
        float4 pv = ((const float4*)pb)[o4];
        *(float4*)&xs[row * 68 + col] = xv;
        *(float4*)&ps[row * 68 + col] = pv;
    }
    __syncthreads();
    {
        int mg = t >> 6, d = t & 63;
        float s = 0.f;
        #pragma unroll
        for (int p = 0; p < 16; ++p) s += ps[(mg * 16 + p) * 68 + d];
        red[t] = s;
        int m = t >> 2, q = t & 3;
        float ss = 0.f;
        #pragma unroll
        for (int j = 0; j < 16; ++j) { float v = xs[m * 68 + q * 16 + j]; ss += v * v; }
        red2[t] = ss;
    }
    __syncthreads();
    if (t < 64) {
        pm[t] = (red[t] + red[t + 64] + red[t + 128] + red[t + 192]) * (1.0f / 64.0f);
        float s = red2[t * 4] + red2[t * 4 + 1] + red2[t * 4 + 2] + red2[t * 4 + 3];
        rs[t] = 1.0f / sqrtf(s * (1.0f / 64.0f) + EPS);
    }
    __syncthreads();
    {
        int m = t >> 2, q = t & 3;
        float sc = rs[m];
        #pragma unroll
        for (int j = 0; j < 16; ++j) {
            int d = q * 16 + j;
            int a = m * 68 + d;
            xs[a] = xs[a] * sc * nw[d] + (ps[a] - pm[d]);
        }
    }
    __syncthreads();
    {
        int mg = t >> 6, d = t & 63;
        float s = 0.f;
        #pragma unroll
        for (int p = 0; p < 16; ++p) s += xs[(mg * 16 + p) * 68 + d];
        red[t] = s;
        float* a2b = A2 + blk * 4096;
        #pragma unroll
        for (int it = 0; it < 16; ++it) {
            int o = t + it * 256;              // o = h*512 + m*8 + e
            int e = o & 7, m = (o >> 3) & 63, hh = o >> 9;
            a2b[o] = xs[m * 68 + hh * 8 + e];
        }
    }
    __syncthreads();
    if (t < 64) {
        float s = red[t] + red[t + 64] + red[t + 128] + red[t + 192];
        bm2[(t >> 3) * 1024 + blk * 8 + (t & 7)] = s * (1.0f / 64.0f);
    }
}

// ---------------------------------------------------------------------------
// K2: routing (top-2, exact jax tie semantics) + attention + residual.
// 16 lanes per (point,head); K-data held in registers across both passes.
// ---------------------------------------------------------------------------
__global__ __launch_bounds__(256) void k_attn(
    const float* __restrict__ x, const float* __restrict__ A2,
    const float* __restrict__ bm2, float* __restrict__ hws)
{
    int h = blockIdx.x >> 9;
    int i = ((blockIdx.x & 511) << 4) + (threadIdx.x >> 4);
    int lane = threadIdx.x & 15;
    int bi = i >> 6, mi = i & 63;

    int off = i * 64 + h * 8 + (lane & 7);
    float xres = x[off];                           // prefetch residual term

    const float* qp = A2 + ((bi * 8 + h) * 64 + mi) * 8;
    float4 qa = ((const float4*)qp)[0];
    float4 qb = ((const float4*)qp)[1];

    // ---- routing: top-2 over 128 ball-mean keys (float4 loads) ----
    const float* bmh = bm2 + h * 1024;
    float bv0 = -3.4e38f, bv1 = -3.4e38f;
    int ix0 = 0, ix1 = 0;
    #pragma unroll
    for (int j = 0; j < 8; ++j) {
        int b = lane + j * 16;
        float4 f0 = ((const float4*)(bmh + b * 8))[0];
        float4 f1 = ((const float4*)(bmh + b * 8))[1];
        float lg = qa.x*f0.x + qa.y*f0.y + qa.z*f0.z + qa.w*f0.w
                 + qb.x*f1.x + qb.y*f1.y + qb.z*f1.z + qb.w*f1.w;
        if (lg > bv0)      { bv1 = bv0; ix1 = ix0; bv0 = lg; ix0 = b; }
        else if (lg > bv1) { bv1 = lg; ix1 = b; }
    }
    #pragma unroll
    for (int st = 1; st < 16; st <<= 1) {
        float ov0 = __shfl_xor(bv0, st); int oi0 = __shfl_xor(ix0, st);
        float ov1 = __shfl_xor(bv1, st); int oi1 = __shfl_xor(ix1, st);
        bool aw = (bv0 > ov0) || (bv0 == ov0 && ix0 < oi0);
        if (aw) {
            if ((ov0 > bv1) || (ov0 == bv1 && oi0 < ix1)) { bv1 = ov0; ix1 = oi0; }
        } else {
            if ((bv0 > ov1) || (bv0 == ov1 && ix0 < oi1)) { bv1 = bv0; ix1 = ix0; }
            else                                          { bv1 = ov1; ix1 = oi1; }
            bv0 = ov0; ix0 = oi0;
        }
    }

    // ---- load both balls' K-slices into registers, compute scores ----
    const float* k0 = A2 + (ix0 * 8 + h) * 512;
    const float* k1 = A2 + (ix1 * 8 + h) * 512;
    const float SC = 0.35355339059327373f;         // EH^-0.5
    float4 k0a[4], k0b[4], k1a[4], k1b[4];
    float s0[4], s1[4];
    float mx = -3.4e38f;
    #pragma unroll
    for (int jj = 0; jj < 4; ++jj) {
        int m = lane + jj * 16;
        k0a[jj] = ((const float4*)(k0 + m * 8))[0];
        k0b[jj] = ((const float4*)(k0 + m * 8))[1];
        k1a[jj] = ((const float4*)(k1 + m * 8))[0];
        k1b[jj] = ((const float4*)(k1 + m * 8))[1];
        float d0 = qa.x*k0a[jj].x + qa.y*k0a[jj].y + qa.z*k0a[jj].z + qa.w*k0a[jj].w
                 + qb.x*k0b[jj].x + qb.y*k0b[jj].y + qb.z*k0b[jj].z + qb.w*k0b[jj].w;
        s0[jj] = d0 * SC;
        float d1 = qa.x*k1a[jj].x + qa.y*k1a[jj].y + qa.z*k1a[jj].z + qa.w*k1a[jj].w
                 + qb.x*k1b[jj].x + qb.y*k1b[jj].y + qb.z*k1b[jj].z + qb.w*k1b[jj].w;
        s1[jj] = d1 * SC;
        mx = fmaxf(mx, fmaxf(s0[jj], s1[jj]));
    }
    #pragma unroll
    for (int st = 1; st < 16; st <<= 1) mx = fmaxf(mx, __shfl_xor(mx, st));
    float sum = 0.f;
    #pragma unroll
    for (int jj = 0; jj < 4; ++jj) {
        s0[jj] = __expf(s0[jj] - mx); sum += s0[jj];
        s1[jj] = __expf(s1[jj] - mx); sum += s1[jj];
    }
    #pragma unroll
    for (int st = 1; st < 16; st <<= 1) sum += __shfl_xor(sum, st);
    float inv = 1.0f / sum;

    float acc[8] = {0,0,0,0,0,0,0,0};
    #pragma unroll
    for (int jj = 0; jj < 4; ++jj) {
        float p = s0[jj] * inv;
        acc[0] += p*k0a[jj].x; acc[1] += p*k0a[jj].y; acc[2] += p*k0a[jj].z; acc[3] += p*k0a[jj].w;
        acc[4] += p*k0b[jj].x; acc[5] += p*k0b[jj].y; acc[6] += p*k0b[jj].z; acc[7] += p*k0b[jj].w;
        float p2 = s1[jj] * inv;
        acc[0] += p2*k1a[jj].x; acc[1] += p2*k1a[jj].y; acc[2] += p2*k1a[jj].z; acc[3] += p2*k1a[jj].w;
        acc[4] += p2*k1b[jj].x; acc[5] += p2*k1b[jj].y; acc[6] += p2*k1b[jj].z; acc[7] += p2*k1b[jj].w;
    }
    #pragma unroll
    for (int st = 1; st < 16; st <<= 1) {
        #pragma unroll
        for (int e = 0; e < 8; ++e) acc[e] += __shfl_xor(acc[e], st);
    }
    if (lane < 8) {
        float v = acc[0];
        #pragma unroll
        for (int e = 1; e < 8; ++e) if (lane == e) v = acc[e];
        hws[off] = xres + v;
    }
}

// ---------------------------------------------------------------------------
// K3: rmsnorm + SwiGLU + residual. 8 rows/wave, float2 weights, readlane
// broadcast for W1/W2 phase, wave-private LDS broadcast of hid for W3 phase
// (uniform-address ds_read, no barrier: each wave reads only its own region).
// ---------------------------------------------------------------------------
__global__ __launch_bounds__(256) void k_mlp(
    const float* __restrict__ hws, const float* __restrict__ n2w,
    const float* __restrict__ w12, const float* __restrict__ b1,
    const float* __restrict__ b2,  const float* __restrict__ w3P,
    const float* __restrict__ b3,  float* __restrict__ out)
{
    __shared__ float hidL[4][8][256];              // 32 KB, wave-private slices
    int lane = threadIdx.x & 63;
    int wv = threadIdx.x >> 6;
    int r0 = (blockIdx.x * 4 + wv) * 8;

    const float2* w12v = (const float2*)w12;
    const float2* w3v  = (const float2*)w3P;

    float hreg[8], hn[8];
    float nw = n2w[lane];
    #pragma unroll
    for (int r = 0; r < 8; ++r) hreg[r] = hws[(r0 + r) * 64 + lane];
    #pragma unroll
    for (int r = 0; r < 8; ++r) {
        float s = hreg[r] * hreg[r];
        #pragma unroll
        for (int st = 1; st < 64; st <<= 1) s += __shfl_xor(s, st);
        float sc = 1.0f / sqrtf(s * (1.0f / 64.0f) + EPS);
        hn[r] = hreg[r] * sc * nw;
    }

    float a1[32], a2[32];                          // [u*8+r]
    #pragma unroll
    for (int z = 0; z < 32; ++z) { a1[z] = 0.f; a2[z] = 0.f; }
    #pragma unroll 4
    for (int e = 0; e < 64; ++e) {
        float2 wv0 = w12v[e * 256 + lane];
        float2 wv1 = w12v[e * 256 + 64 + lane];
        float2 wv2 = w12v[e * 256 + 128 + lane];
        float2 wv3 = w12v[e * 256 + 192 + lane];
        #pragma unroll
        for (int r = 0; r < 8; ++r) {
            float hb = rdlane(hn[r], e);
            a1[r]      = fmaf(hb, wv0.x, a1[r]);      a2[r]      = fmaf(hb, wv0.y, a2[r]);
            a1[8 + r]  = fmaf(hb, wv1.x, a1[8 + r]);  a2[8 + r]  = fmaf(hb, wv1.y, a2[8 + r]);
            a1[16 + r] = fmaf(hb, wv2.x, a1[16 + r]); a2[16 + r] = fmaf(hb, wv2.y, a2[16 + r]);
            a1[24 + r] = fmaf(hb, wv3.x, a1[24 + r]); a2[24 + r] = fmaf(hb, wv3.y, a2[24 + r]);
        }
    }

    // silu + gate, write hid to this wave's LDS slice
    #pragma unroll
    for (int u = 0; u < 4; ++u) {
        float bb1 = b1[u * 64 + lane], bb2 = b2[u * 64 + lane];
        #pragma unroll
        for (int r = 0; r < 8; ++r) {
            float z = a1[u * 8 + r] + bb1;
            float g = z * __builtin_amdgcn_rcpf(1.0f + __expf(-z));   // silu
            hidL[wv][r][u * 64 + lane] = (a2[u * 8 + r] + bb2) * g;
        }
    }

    float acc[8] = {0,0,0,0,0,0,0,0};
    #pragma unroll
    for (int u = 0; u < 4; ++u) {
        #pragma unroll 8
        for (int kp = 0; kp < 32; ++kp) {
            float2 w = w3v[(u * 32 + kp) * 64 + lane];
            #pragma unroll
            for (int r = 0; r < 8; ++r) {
                float2 hh = *(const float2*)&hidL[wv][r][u * 64 + kp * 2]; // uniform addr → broadcast
                acc[r] = fmaf(hh.x, w.x, acc[r]);
                acc[r] = fmaf(hh.y, w.y, acc[r]);
            }
        }
    }
    float b3vv = b3[lane];
    #pragma unroll
    for (int r = 0; r < 8; ++r)
        out[(r0 + r) * 64 + lane] = hreg[r] + acc[r] + b3vv;
}

// ---------------------------------------------------------------------------
// INSTRUMENTATION ROUND: launch the (pure, idempotent) pipeline TWICE.
// kernel_total = dur(this) - dur(next, single);  floor = 2*dur(next) - dur(this)
// ---------------------------------------------------------------------------
extern "C" void kernel_launch(void* const* d_in, const int* in_sizes, int n_in,
                              void* d_out, int out_size, void* d_ws, size_t ws_size,
                              hipStream_t stream)
{
    const float* x   = (const float*)d_in[0];
    const float* pos = (const float*)d_in[1];
    const float* n1w = (const float*)d_in[2];
    const float* n2w = (const float*)d_in[3];
    const float* w1  = (const float*)d_in[4];
    const float* b1  = (const float*)d_in[5];
    const float* w2  = (const float*)d_in[6];
    const float* b2  = (const float*)d_in[7];
    const float* w3  = (const float*)d_in[8];
    const float* b3  = (const float*)d_in[9];
    float* outp = (float*)d_out;
    float* ws = (float*)d_ws;

    float* A2  = ws;                 // 524288 floats
    float* bm2 = ws + 524288;        // 8192: routing keys [h][b][e]
    float* hws = ws + 532480;        // 524288
    float* w12 = ws + 1056768;       // 32768: w1/w2 interleaved, [e][u][l][2]
    float* w3P = ws + 1089536;       // 16384: [kp][l][2]

    for (int rep = 0; rep < 2; ++rep) {
        k_prep<<<dim3(176), dim3(256), 0, stream>>>(x, pos, n1w, w1, w2, w3,
                                                    A2, bm2, w12, w3P);
        k_attn<<<dim3(4096), dim3(256), 0, stream>>>(x, A2, bm2, hws);
        k_mlp<<<dim3(256), dim3(256), 0, stream>>>(hws, n2w, w12, b1, b2,
                                                   w3P, b3, outp);
    }
}

// Round 4
// 124.424 us; speedup vs baseline: 1.7572x; 1.7572x over previous
//
#include <hip/hip_runtime.h>
#include <math.h>

#define NPTS 8192
#define NB   128
#define EPS  1.1920929e-07f

__device__ __forceinline__ float rdlane(float v, int l) {
    return __int_as_float(__builtin_amdgcn_readlane(__float_as_int(v), l));
}

// ---------------------------------------------------------------------------
// K1: per-ball prep:  a = rmsnorm(x)*n1w + (pos - ball_mean(pos))
//     A2[b][h][m][e] (each (b,h) slice contiguous 2KB)
//     bm2[h][b][e]   routing keys (per-lane float4-loadable)
//     blocks >= NB pack MLP weights: w12 (w1/w2 interleaved), w3P (k-paired).
// ---------------------------------------------------------------------------
__global__ __launch_bounds__(256) void k_prep(
    const float* __restrict__ x, const float* __restrict__ pos,
    const float* __restrict__ n1w,
    const float* __restrict__ w1, const float* __restrict__ w2,
    const float* __restrict__ w3,
    float* __restrict__ A2, float* __restrict__ bm2,
    float* __restrict__ w12, float* __restrict__ w3P)
{
    int t = threadIdx.x;
    int blk = blockIdx.x;
    if (blk >= NB) {
        int base = (blk - NB) * 1024 + t * 4;
        #pragma unroll
        for (int c = 0; c < 4; ++c) {
            int idx = base + c;
            if (idx < 32768) {
                // w12[e*512 + u*128 + l*2 + s] = (s?w2:w1)[(u*64+l)*64 + e]
                int s = idx & 1, l = (idx >> 1) & 63, u = (idx >> 7) & 3, e = idx >> 9;
                w12[idx] = (s ? w2 : w1)[(u * 64 + l) * 64 + e];
            } else {
                // w3P[kp*128 + l*2 + s] = w3[l*256 + kp*2 + s]
                int o = idx - 32768;
                int s = o & 1, l = (o >> 1) & 63, kp = o >> 7;
                w3P[o] = w3[l * 256 + kp * 2 + s];
            }
        }
        return;
    }
    __shared__ float xs[64 * 68];
    __shared__ float ps[64 * 68];
    __shared__ float red[256], red2[256];
    __shared__ float pm[64], rs[64], nw[64];

    const float* xb = x + blk * 4096;
    const float* pb = pos + blk * 4096;
    if (t < 64) nw[t] = n1w[t];
    #pragma unroll
    for (int it = 0; it < 4; ++it) {
        int o4 = t + it * 256;
        int row = o4 >> 4, col = (o4 & 15) * 4;
        float4 xv = ((const float4*)xb)[o4];
        float4 pv = ((const float4*)pb)[o4];
        *(float4*)&xs[row * 68 + col] = xv;
        *(float4*)&ps[row * 68 + col] = pv;
    }
    __syncthreads();
    {
        int mg = t >> 6, d = t & 63;
        float s = 0.f;
        #pragma unroll
        for (int p = 0; p < 16; ++p) s += ps[(mg * 16 + p) * 68 + d];
        red[t] = s;
        int m = t >> 2, q = t & 3;
        float ss = 0.f;
        #pragma unroll
        for (int j = 0; j < 16; ++j) { float v = xs[m * 68 + q * 16 + j]; ss += v * v; }
        red2[t] = ss;
    }
    __syncthreads();
    if (t < 64) {
        pm[t] = (red[t] + red[t + 64] + red[t + 128] + red[t + 192]) * (1.0f / 64.0f);
        float s = red2[t * 4] + red2[t * 4 + 1] + red2[t * 4 + 2] + red2[t * 4 + 3];
        rs[t] = 1.0f / sqrtf(s * (1.0f / 64.0f) + EPS);
    }
    __syncthreads();
    {
        int m = t >> 2, q = t & 3;
        float sc = rs[m];
        #pragma unroll
        for (int j = 0; j < 16; ++j) {
            int d = q * 16 + j;
            int a = m * 68 + d;
            xs[a] = xs[a] * sc * nw[d] + (ps[a] - pm[d]);
        }
    }
    __syncthreads();
    {
        int mg = t >> 6, d = t & 63;
        float s = 0.f;
        #pragma unroll
        for (int p = 0; p < 16; ++p) s += xs[(mg * 16 + p) * 68 + d];
        red[t] = s;
        float* a2b = A2 + blk * 4096;
        #pragma unroll
        for (int it = 0; it < 16; ++it) {
            int o = t + it * 256;              // o = h*512 + m*8 + e
            int e = o & 7, m = (o >> 3) & 63, hh = o >> 9;
            a2b[o] = xs[m * 68 + hh * 8 + e];
        }
    }
    __syncthreads();
    if (t < 64) {
        float s = red[t] + red[t + 64] + red[t + 128] + red[t + 192];
        bm2[(t >> 3) * 1024 + blk * 8 + (t & 7)] = s * (1.0f / 64.0f);
    }
}

// ---------------------------------------------------------------------------
// K2: routing (top-2, exact jax tie semantics) + attention + residual.
// 16 lanes per (point,head); K-data held in registers across both passes.
// ---------------------------------------------------------------------------
__global__ __launch_bounds__(256) void k_attn(
    const float* __restrict__ x, const float* __restrict__ A2,
    const float* __restrict__ bm2, float* __restrict__ hws)
{
    int h = blockIdx.x >> 9;
    int i = ((blockIdx.x & 511) << 4) + (threadIdx.x >> 4);
    int lane = threadIdx.x & 15;
    int bi = i >> 6, mi = i & 63;

    int off = i * 64 + h * 8 + (lane & 7);
    float xres = x[off];                           // prefetch residual term

    const float* qp = A2 + ((bi * 8 + h) * 64 + mi) * 8;
    float4 qa = ((const float4*)qp)[0];
    float4 qb = ((const float4*)qp)[1];

    // ---- routing: top-2 over 128 ball-mean keys (float4 loads) ----
    const float* bmh = bm2 + h * 1024;
    float bv0 = -3.4e38f, bv1 = -3.4e38f;
    int ix0 = 0, ix1 = 0;
    #pragma unroll
    for (int j = 0; j < 8; ++j) {
        int b = lane + j * 16;
        float4 f0 = ((const float4*)(bmh + b * 8))[0];
        float4 f1 = ((const float4*)(bmh + b * 8))[1];
        float lg = qa.x*f0.x + qa.y*f0.y + qa.z*f0.z + qa.w*f0.w
                 + qb.x*f1.x + qb.y*f1.y + qb.z*f1.z + qb.w*f1.w;
        if (lg > bv0)      { bv1 = bv0; ix1 = ix0; bv0 = lg; ix0 = b; }
        else if (lg > bv1) { bv1 = lg; ix1 = b; }
    }
    #pragma unroll
    for (int st = 1; st < 16; st <<= 1) {
        float ov0 = __shfl_xor(bv0, st); int oi0 = __shfl_xor(ix0, st);
        float ov1 = __shfl_xor(bv1, st); int oi1 = __shfl_xor(ix1, st);
        bool aw = (bv0 > ov0) || (bv0 == ov0 && ix0 < oi0);
        if (aw) {
            if ((ov0 > bv1) || (ov0 == bv1 && oi0 < ix1)) { bv1 = ov0; ix1 = oi0; }
        } else {
            if ((bv0 > ov1) || (bv0 == ov1 && ix0 < oi1)) { bv1 = bv0; ix1 = ix0; }
            else                                          { bv1 = ov1; ix1 = oi1; }
            bv0 = ov0; ix0 = oi0;
        }
    }

    // ---- load both balls' K-slices into registers, compute scores ----
    const float* k0 = A2 + (ix0 * 8 + h) * 512;
    const float* k1 = A2 + (ix1 * 8 + h) * 512;
    const float SC = 0.35355339059327373f;         // EH^-0.5
    float4 k0a[4], k0b[4], k1a[4], k1b[4];
    float s0[4], s1[4];
    float mx = -3.4e38f;
    #pragma unroll
    for (int jj = 0; jj < 4; ++jj) {
        int m = lane + jj * 16;
        k0a[jj] = ((const float4*)(k0 + m * 8))[0];
        k0b[jj] = ((const float4*)(k0 + m * 8))[1];
        k1a[jj] = ((const float4*)(k1 + m * 8))[0];
        k1b[jj] = ((const float4*)(k1 + m * 8))[1];
        float d0 = qa.x*k0a[jj].x + qa.y*k0a[jj].y + qa.z*k0a[jj].z + qa.w*k0a[jj].w
                 + qb.x*k0b[jj].x + qb.y*k0b[jj].y + qb.z*k0b[jj].z + qb.w*k0b[jj].w;
        s0[jj] = d0 * SC;
        float d1 = qa.x*k1a[jj].x + qa.y*k1a[jj].y + qa.z*k1a[jj].z + qa.w*k1a[jj].w
                 + qb.x*k1b[jj].x + qb.y*k1b[jj].y + qb.z*k1b[jj].z + qb.w*k1b[jj].w;
        s1[jj] = d1 * SC;
        mx = fmaxf(mx, fmaxf(s0[jj], s1[jj]));
    }
    #pragma unroll
    for (int st = 1; st < 16; st <<= 1) mx = fmaxf(mx, __shfl_xor(mx, st));
    float sum = 0.f;
    #pragma unroll
    for (int jj = 0; jj < 4; ++jj) {
        s0[jj] = __expf(s0[jj] - mx); sum += s0[jj];
        s1[jj] = __expf(s1[jj] - mx); sum += s1[jj];
    }
    #pragma unroll
    for (int st = 1; st < 16; st <<= 1) sum += __shfl_xor(sum, st);
    float inv = 1.0f / sum;

    float acc[8] = {0,0,0,0,0,0,0,0};
    #pragma unroll
    for (int jj = 0; jj < 4; ++jj) {
        float p = s0[jj] * inv;
        acc[0] += p*k0a[jj].x; acc[1] += p*k0a[jj].y; acc[2] += p*k0a[jj].z; acc[3] += p*k0a[jj].w;
        acc[4] += p*k0b[jj].x; acc[5] += p*k0b[jj].y; acc[6] += p*k0b[jj].z; acc[7] += p*k0b[jj].w;
        float p2 = s1[jj] * inv;
        acc[0] += p2*k1a[jj].x; acc[1] += p2*k1a[jj].y; acc[2] += p2*k1a[jj].z; acc[3] += p2*k1a[jj].w;
        acc[4] += p2*k1b[jj].x; acc[5] += p2*k1b[jj].y; acc[6] += p2*k1b[jj].z; acc[7] += p2*k1b[jj].w;
    }
    #pragma unroll
    for (int st = 1; st < 16; st <<= 1) {
        #pragma unroll
        for (int e = 0; e < 8; ++e) acc[e] += __shfl_xor(acc[e], st);
    }
    if (lane < 8) {
        float v = acc[0];
        #pragma unroll
        for (int e = 1; e < 8; ++e) if (lane == e) v = acc[e];
        hws[off] = xres + v;
    }
}

// ---------------------------------------------------------------------------
// K3: rmsnorm + SwiGLU + residual. BLOCK owns 8 rows; the 4 waves split the
// hidden dim (wave wv -> hidden units wv*64..wv*64+63) in phase A, and split
// W3's K-dim the same way in phase B with an LDS partial-sum combine.
// Grid 1024 blocks -> 4096 waves = 4/SIMD (was 1/SIMD = the 58us stall).
// ---------------------------------------------------------------------------
__global__ __launch_bounds__(256) void k_mlp(
    const float* __restrict__ hws, const float* __restrict__ n2w,
    const float* __restrict__ w12, const float* __restrict__ b1,
    const float* __restrict__ b2,  const float* __restrict__ w3P,
    const float* __restrict__ b3,  float* __restrict__ out)
{
    __shared__ float hidS[8][256];                 // 8KB
    __shared__ float redS[4][8][64];               // 8KB
    int lane = threadIdx.x & 63;
    int wv = threadIdx.x >> 6;
    int r0 = blockIdx.x * 8;

    const float2* w12v = (const float2*)w12;
    const float2* w3v  = (const float2*)w3P;

    float nw = n2w[lane];
    float hreg[8], hn[8];
    #pragma unroll
    for (int r = 0; r < 8; ++r) hreg[r] = hws[(r0 + r) * 64 + lane];
    #pragma unroll
    for (int r = 0; r < 8; ++r) {
        float s = hreg[r] * hreg[r];
        #pragma unroll
        for (int st = 1; st < 64; st <<= 1) s += __shfl_xor(s, st);
        float sc = 1.0f / sqrtf(s * (1.0f / 64.0f) + EPS);
        hn[r] = hreg[r] * sc * nw;
    }

    // ---- phase A: this wave's 64 hidden units of W1 and W2 ----
    float a1[8], a2[8];
    #pragma unroll
    for (int r = 0; r < 8; ++r) { a1[r] = 0.f; a2[r] = 0.f; }
    #pragma unroll 4
    for (int e = 0; e < 64; ++e) {
        float2 w = w12v[e * 256 + wv * 64 + lane];
        #pragma unroll
        for (int r = 0; r < 8; ++r) {
            float hb = rdlane(hn[r], e);
            a1[r] = fmaf(hb, w.x, a1[r]);
            a2[r] = fmaf(hb, w.y, a2[r]);
        }
    }
    {
        float bb1 = b1[wv * 64 + lane], bb2 = b2[wv * 64 + lane];
        #pragma unroll
        for (int r = 0; r < 8; ++r) {
            float z = a1[r] + bb1;
            float g = z * __builtin_amdgcn_rcpf(1.0f + __expf(-z));   // silu
            hidS[r][wv * 64 + lane] = (a2[r] + bb2) * g;
        }
    }
    __syncthreads();

    // ---- phase B: partial W3 over this wave's K-slice (k = wv*64 .. +63) ----
    float acc[8] = {0,0,0,0,0,0,0,0};
    #pragma unroll 8
    for (int kp = 0; kp < 32; ++kp) {
        float2 w = w3v[(wv * 32 + kp) * 64 + lane];
        #pragma unroll
        for (int r = 0; r < 8; ++r) {
            float2 hh = *(const float2*)&hidS[r][wv * 64 + kp * 2]; // uniform addr -> broadcast
            acc[r] = fmaf(hh.x, w.x, acc[r]);
            acc[r] = fmaf(hh.y, w.y, acc[r]);
        }
    }
    #pragma unroll
    for (int r = 0; r < 8; ++r) redS[wv][r][lane] = acc[r];
    __syncthreads();

    // ---- finalize: wave wv sums partials for rows 2wv, 2wv+1 ----
    float b3vv = b3[lane];
    #pragma unroll
    for (int rr = 0; rr < 2; ++rr) {
        int r = wv * 2 + rr;
        float v = (redS[0][r][lane] + redS[1][r][lane])
                + (redS[2][r][lane] + redS[3][r][lane]);
        out[(r0 + r) * 64 + lane] = hreg[r] + v + b3vv;
    }
}

// ---------------------------------------------------------------------------
extern "C" void kernel_launch(void* const* d_in, const int* in_sizes, int n_in,
                              void* d_out, int out_size, void* d_ws, size_t ws_size,
                              hipStream_t stream)
{
    const float* x   = (const float*)d_in[0];
    const float* pos = (const float*)d_in[1];
    const float* n1w = (const float*)d_in[2];
    const float* n2w = (const float*)d_in[3];
    const float* w1  = (const float*)d_in[4];
    const float* b1  = (const float*)d_in[5];
    const float* w2  = (const float*)d_in[6];
    const float* b2  = (const float*)d_in[7];
    const float* w3  = (const float*)d_in[8];
    const float* b3  = (const float*)d_in[9];
    float* outp = (float*)d_out;
    float* ws = (float*)d_ws;

    float* A2  = ws;                 // 524288 floats
    float* bm2 = ws + 524288;        // 8192: routing keys [h][b][e]
    float* hws = ws + 532480;        // 524288
    float* w12 = ws + 1056768;       // 32768: w1/w2 interleaved, [e][u][l][2]
    float* w3P = ws + 1089536;       // 16384: [kp][l][2]

    k_prep<<<dim3(176), dim3(256), 0, stream>>>(x, pos, n1w, w1, w2, w3,
                                                A2, bm2, w12, w3P);
    k_attn<<<dim3(4096), dim3(256), 0, stream>>>(x, A2, bm2, hws);
    k_mlp<<<dim3(1024), dim3(256), 0, stream>>>(hws, n2w, w12, b1, b2,
                                                w3P, b3, outp);
}